// Round 13
// baseline (915.905 us; speedup 1.0000x reference)
//
#include <hip/hip_runtime.h>

// WaveRNN: 2D wave equation, T=512 steps, B=4 batches of 160x160.
// R9 base (NBK=4, OWN=40, D_EX=20, validated exchange protocol) + 2-STEP
// TEMPORAL BLOCKING: each round advances 2 steps with ONE barrier.
// Step 1: interim W (7x7 = owned 5x5 + ring 1) from h1 halo +-2 rows (LDS) and
// h2 halo +-1 rows (LDS); columns via chained DPP shifts (VALU, not LDS pipe).
// Step 2: consumes W entirely in-lane (ring copies bitwise-match neighbors).
// LDS publishes per thread: h1 rows 0,1,3,4 + h2 rows 0,4 (6 edge arrays,
// double-buffered parity). Probes/source for both sub-steps; exchange code
// and slab protocol byte-identical to R9.

#define NB   4
#define NBK  4          // blocks per batch
#define OWN  40         // owned rows per block
#define D_EX 20         // halo depth == steps between exchanges (even)
#define NT   512
#define NN   160
#define NP   32
#define C_DT 0.16f

#define TGX   32
#define TPR   16                 // patch-rows (interior: (40+2*20)/5)
#define NTHR  (TPR*TGX)          // 512
#define NSLOT (TPR + 2)          // 18; slot 0 and 17 are permanent zero guards
#define K_ENT 6

#define SLAB      (D_EX*NN)              // floats per (side,level) slab: 3200
#define GB_FLOATS (NB*NBK*2*2*SLAB)      // 204800 floats = 819200 B
#define FLAG_OFF  (GB_FLOATS*4)          // byte offset of flags in d_ws

typedef float f4 __attribute__((ext_vector_type(4)));

#if defined(__has_builtin)
#if __has_builtin(__builtin_amdgcn_update_dpp)
#define HAVE_DPP 1
#endif
#endif

__device__ __forceinline__ float shr1(float v) {   // lane i <- lane i-1
#ifdef HAVE_DPP
    return __int_as_float(__builtin_amdgcn_update_dpp(
        0, __float_as_int(v), 0x138 /*wave_shr:1*/, 0xf, 0xf, true));
#else
    return __shfl_up(v, 1, 64);
#endif
}
__device__ __forceinline__ float shl1(float v) {   // lane i <- lane i+1
#ifdef HAVE_DPP
    return __int_as_float(__builtin_amdgcn_update_dpp(
        0, __float_as_int(v), 0x130 /*wave_shl:1*/, 0xf, 0xf, true));
#else
    return __shfl_down(v, 1, 64);
#endif
}

// 5-float patch row -> 9 columns (-2..6), horizontal halos via DPP
#define BROW9(dst, v0,v1,v2,v3,v4) {                                          \
    dst[2]=(v0); dst[3]=(v1); dst[4]=(v2); dst[5]=(v3); dst[6]=(v4);          \
    const float _m2 = shr1((v3)), _m1 = shr1((v4));                           \
    const float _p5 = shl1((v0)), _p6 = shl1((v1));                           \
    dst[0]=(cg==0)?0.0f:_m2;      dst[1]=(cg==0)?0.0f:_m1;                    \
    dst[7]=(cg==TGX-1)?0.0f:_p5;  dst[8]=(cg==TGX-1)?0.0f:_p6; }

// 5-float patch row -> 7 columns (-1..5)
#define BROW7(dst, v0,v1,v2,v3,v4) {                                          \
    dst[1]=(v0); dst[2]=(v1); dst[3]=(v2); dst[4]=(v3); dst[5]=(v4);          \
    const float _m1 = shr1((v4)); const float _p5 = shl1((v0));               \
    dst[0]=(cg==0)?0.0f:_m1;      dst[6]=(cg==TGX-1)?0.0f:_p5; }

__global__ __launch_bounds__(NTHR, 1) void wave_kernel(
    const float* __restrict__ x,      // [B][T]
    const float* __restrict__ cmat,   // [N][N]
    const float* __restrict__ rho,    // [N][N]
    const int*   __restrict__ src_i_p,
    const int*   __restrict__ src_j_p,
    const int*   __restrict__ probe_i,// [P]
    const int*   __restrict__ probe_j,// [P]
    float*       __restrict__ y,      // [B][T][P]
    float*       __restrict__ gw,     // exchange slabs
    int*         __restrict__ flags)  // [B*NBK], zeroed per launch
{
    // edge arrays, e: 0=h1row0 1=h1row1 2=h1row3 3=h1row4 4=h2row0 5=h2row4
    __shared__ f4    L4[2][6][NSLOT][TGX];
    __shared__ float L1[2][6][NSLOT][TGX];
    __shared__ float xbuf[NT];
    __shared__ int   pco[2*NP];

    const int bid   = blockIdx.x;
    const int batch = bid & 7;
    if (batch >= NB) return;
    const int blk   = bid >> 3;

    const int own_s = blk * OWN;
    const int own_e = own_s + OWN;
    const int ext_s = (own_s - D_EX < 0)  ? 0  : own_s - D_EX;
    const int ext_e = (own_e + D_EX > NN) ? NN : own_e + D_EX;
    const int npr   = (ext_e - ext_s) / 5;

    const int tid = threadIdx.x;
    const int pr  = tid >> 5;
    const int cg  = tid & 31;
    const bool act = pr < npr;
    const int gr0 = ext_s + 5*pr;
    const int c0  = 5*cg;

    // ---- init LDS (zeros = correct zero initial state halos) ----
    {
        float* z4 = (float*)&L4[0][0][0][0];
        for (int i = tid; i < 2*6*NSLOT*TGX*4; i += NTHR) z4[i] = 0.0f;
        float* z1 = &L1[0][0][0][0];
        for (int i = tid; i < 2*6*NSLOT*TGX; i += NTHR) z1[i] = 0.0f;
        for (int i = tid; i < NT; i += NTHR) xbuf[i] = x[batch*NT + i];
        if (tid < NP) { pco[tid] = probe_i[tid]; pco[NP + tid] = probe_j[tid]; }
    }

    const int si = src_i_p[0];
    const int sj = src_j_p[0];

    float hA[5][5], hB[5][5], cfx[7][7];
    #pragma unroll
    for (int ii = -1; ii <= 5; ++ii)
        #pragma unroll
        for (int jj = -1; jj <= 5; ++jj) {
            float cfv = 0.0f;
            const int r = gr0 + ii, c = c0 + jj;
            if (act && r >= 0 && r < NN && c >= 0 && c < NN) {
                const float cc = cmat[r*NN + c];
                const float rr = rho[r*NN + c];
                cfv = C_DT * cc * cc / rr;
            }
            cfx[ii+1][jj+1] = cfv;
        }
    #pragma unroll
    for (int i = 0; i < 5; ++i)
        #pragma unroll
        for (int j = 0; j < 5; ++j) { hA[i][j] = 0.0f; hB[i][j] = 0.0f; }

    unsigned srcMask = 0;          // owned 5x5, for step-2 injection
    if (act && gr0 <= si && si < gr0 + 5 && c0 <= sj && sj < c0 + 5)
        srcMask = 1u << ((si - gr0)*5 + (sj - c0));
    unsigned long long srcW = 0ull; // extended 7x7, for step-1 injection
    if (act) {
        for (int ii = -1; ii <= 5; ++ii)
            for (int jj = -1; jj <= 5; ++jj)
                if (gr0 + ii == si && c0 + jj == sj)
                    srcW |= 1ull << ((ii+1)*7 + (jj+1));
    }

    __syncthreads();

    // probe entries over OWNED cells only
    unsigned long long ent = 0;
    int ecnt = 0;
    if (act && gr0 >= own_s && gr0 < own_e) {
        for (int p = 0; p < NP; ++p) {
            const int r = pco[p], c = pco[NP + p];
            if (r >= gr0 && r < gr0 + 5 && c >= c0 && c < c0 + 5) {
                const int ij = (r - gr0)*5 + (c - c0);
                if (ecnt < K_ENT)
                    ent |= ((unsigned long long)(unsigned)(p | (ij << 5))) << (10*ecnt);
                ecnt++;
            }
        }
    }

    // ---- exchange pointers (identical to R9) ----
    const int bid2 = batch*NBK + blk;
    float* sTop = nullptr; float* sBot = nullptr;
    const float* rTop = nullptr; const float* rBot = nullptr;
    if (blk > 0 && gr0 >= own_s && gr0 < own_s + D_EX)
        sTop = gw + (size_t)(bid2*2 + 0)*2*SLAB + (gr0 - own_s)*NN + c0;
    if (blk < NBK-1 && gr0 >= own_e - D_EX && gr0 < own_e)
        sBot = gw + (size_t)(bid2*2 + 1)*2*SLAB + (gr0 - (own_e - D_EX))*NN + c0;
    if (blk > 0 && act && gr0 < own_s)
        rTop = gw + (size_t)((bid2-1)*2 + 1)*2*SLAB + (gr0 - (own_s - D_EX))*NN + c0;
    if (blk < NBK-1 && act && gr0 >= own_e)
        rBot = gw + (size_t)((bid2+1)*2 + 0)*2*SLAB + (gr0 - own_e)*NN + c0;
    int* const flagSelf = &flags[bid2];
    int* const flagUp   = &flags[bid2 - 1];
    int* const flagDn   = &flags[bid2 + 1];

    float* const yb = y + (size_t)batch*NT*NP;

#define PUBLISH(P) {                                                           \
    L4[P][0][pr+1][cg]=(f4){hA[0][0],hA[0][1],hA[0][2],hA[0][3]}; L1[P][0][pr+1][cg]=hA[0][4]; \
    L4[P][1][pr+1][cg]=(f4){hA[1][0],hA[1][1],hA[1][2],hA[1][3]}; L1[P][1][pr+1][cg]=hA[1][4]; \
    L4[P][2][pr+1][cg]=(f4){hA[3][0],hA[3][1],hA[3][2],hA[3][3]}; L1[P][2][pr+1][cg]=hA[3][4]; \
    L4[P][3][pr+1][cg]=(f4){hA[4][0],hA[4][1],hA[4][2],hA[4][3]}; L1[P][3][pr+1][cg]=hA[4][4]; \
    L4[P][4][pr+1][cg]=(f4){hB[0][0],hB[0][1],hB[0][2],hB[0][3]}; L1[P][4][pr+1][cg]=hB[0][4]; \
    L4[P][5][pr+1][cg]=(f4){hB[4][0],hB[4][1],hB[4][2],hB[4][3]}; L1[P][5][pr+1][cg]=hB[4][4]; }

// One round = 2 time steps (t0, t0+1), one barrier.
#define ROUND(T0, PIN, POUT) {                                                 \
    const int t0 = (T0);                                                       \
    /* halo reads: h1 rows -2,-1,5,6 ; h2 rows -1,5 */                         \
    const f4 a2v = L4[PIN][2][pr][cg];   const float a2s = L1[PIN][2][pr][cg]; \
    const f4 a1v = L4[PIN][3][pr][cg];   const float a1s = L1[PIN][3][pr][cg]; \
    const f4 b1v = L4[PIN][5][pr][cg];   const float b1s = L1[PIN][5][pr][cg]; \
    const f4 a5v = L4[PIN][0][pr+2][cg]; const float a5s = L1[PIN][0][pr+2][cg]; \
    const f4 a6v = L4[PIN][1][pr+2][cg]; const float a6s = L1[PIN][1][pr+2][cg]; \
    const f4 b5v = L4[PIN][4][pr+2][cg]; const float b5s = L1[PIN][4][pr+2][cg]; \
    const float xt0 = xbuf[t0], xt1 = xbuf[t0+1];                              \
    float Xw[3][9];   /* rolling h1 rows: slot(r) = (r+2)%3 */                 \
    float W[7][7];    /* interim state t0+0 -> t0+1, rows/cols -1..5 */        \
    BROW9(Xw[0], a2v[0],a2v[1],a2v[2],a2v[3],a2s);                             \
    BROW9(Xw[1], a1v[0],a1v[1],a1v[2],a1v[3],a1s);                             \
    BROW9(Xw[2], hA[0][0],hA[0][1],hA[0][2],hA[0][3],hA[0][4]);                \
    _Pragma("unroll")                                                          \
    for (int wr = -1; wr <= 5; ++wr) {                                         \
        float Yw[7];                                                           \
        if (wr == -1)     { BROW7(Yw, b1v[0],b1v[1],b1v[2],b1v[3],b1s); }      \
        else if (wr == 5) { BROW7(Yw, b5v[0],b5v[1],b5v[2],b5v[3],b5s); }      \
        else { BROW7(Yw, hB[wr][0],hB[wr][1],hB[wr][2],hB[wr][3],hB[wr][4]); } \
        const int sm = (wr+1)%3, sc = (wr+2)%3, sp = (wr+3)%3;                 \
        _Pragma("unroll")                                                      \
        for (int jj = 0; jj < 7; ++jj) {                                       \
            const float s  = (Xw[sm][jj+1] + Xw[sp][jj+1])                     \
                           + (Xw[sc][jj]   + Xw[sc][jj+2]);                    \
            const float h  = Xw[sc][jj+1];                                     \
            const float lap= __builtin_fmaf(-4.0f, h, s);                      \
            const float t1 = __builtin_fmaf(2.0f, h, -Yw[jj]);                 \
            W[wr+1][jj] = __builtin_fmaf(cfx[wr+1][jj], lap, t1);              \
        }                                                                      \
        if (wr <= 4) {  /* build h1 row wr+2 into freed slot sm */             \
            if (wr+2 <= 4) { BROW9(Xw[sm], hA[wr+2][0],hA[wr+2][1],            \
                                 hA[wr+2][2],hA[wr+2][3],hA[wr+2][4]); }       \
            else if (wr+2 == 5) { BROW9(Xw[sm], a5v[0],a5v[1],a5v[2],a5v[3],a5s); } \
            else                { BROW9(Xw[sm], a6v[0],a6v[1],a6v[2],a6v[3],a6s); } \
        }                                                                      \
    }                                                                          \
    if (srcW) {  /* step-1 source injection (ext coords, act-gated mask) */    \
        _Pragma("unroll")                                                      \
        for (int ii = 0; ii < 7; ++ii)                                         \
            _Pragma("unroll")                                                  \
            for (int jj = 0; jj < 7; ++jj)                                     \
                if (srcW & (1ull << (ii*7 + jj))) W[ii][jj] += xt0;            \
    }                                                                          \
    /* step 2: hA <- h(t0+2) in-place; hB <- W owned (h2_new) */               \
    _Pragma("unroll")                                                          \
    for (int i = 0; i < 5; ++i)                                                \
        _Pragma("unroll")                                                      \
        for (int j = 0; j < 5; ++j) {                                          \
            const float s  = (W[i][j+1] + W[i+2][j+1]) + (W[i+1][j] + W[i+1][j+2]); \
            const float h  = W[i+1][j+1];                                      \
            const float lap= __builtin_fmaf(-4.0f, h, s);                      \
            const float t1 = __builtin_fmaf(2.0f, h, -hA[i][j]);               \
            hA[i][j] = __builtin_fmaf(cfx[i+1][j+1], lap, t1);                 \
            hB[i][j] = h;                                                      \
        }                                                                      \
    if (srcMask) {  /* step-2 source injection */                              \
        _Pragma("unroll")                                                      \
        for (int i = 0; i < 5; ++i)                                            \
            _Pragma("unroll")                                                  \
            for (int j = 0; j < 5; ++j)                                        \
                if (srcMask & (1u << (i*5 + j))) hA[i][j] += xt1;              \
    }                                                                          \
    if (ecnt) {  /* probes: t0 from hB (=injected W owned), t0+1 from hA */    \
        float* const yt0 = yb + (size_t)t0 * NP;                               \
        float* const yt1 = yb + (size_t)(t0+1) * NP;                           \
        _Pragma("unroll")                                                      \
        for (int k2 = 0; k2 < K_ENT; ++k2) {                                   \
            if (k2 < ecnt) {                                                   \
                const int e  = (int)((ent >> (10*k2)) & 0x3FF);                \
                const int p  = e & 31;                                         \
                const int ij = e >> 5;                                         \
                float v0 = 0.0f, v1 = 0.0f;                                    \
                _Pragma("unroll")                                              \
                for (int i = 0; i < 5; ++i)                                    \
                    _Pragma("unroll")                                          \
                    for (int j = 0; j < 5; ++j)                                \
                        if (ij == i*5 + j) { v0 = hB[i][j]; v1 = hA[i][j]; }   \
                yt0[p] = v0; yt1[p] = v1;                                      \
            }                                                                  \
        }                                                                      \
    }                                                                          \
    PUBLISH(POUT);                                                             \
    __syncthreads();                                                           \
  }

    int t = 0, g = 0;
    while (t < NT) {
        const int steps = (NT - t < D_EX) ? (NT - t) : D_EX;  // 20 or 12: %4==0
        for (int k = 0; k < steps; k += 4) {
            ROUND(t + k,     0, 1);
            ROUND(t + k + 2, 1, 0);
        }
        t += steps;
        if (t >= NT) break;

        // ---- boundary exchange (h1=hA, h2=hB; t even) — R9 verbatim ----
        if (sTop) {
            #pragma unroll
            for (int i = 0; i < 5; ++i) {
                *(f4*)(sTop + i*NN) = (f4){ hA[i][0], hA[i][1], hA[i][2], hA[i][3] };
                sTop[i*NN + 4] = hA[i][4];
                *(f4*)(sTop + SLAB + i*NN) = (f4){ hB[i][0], hB[i][1], hB[i][2], hB[i][3] };
                sTop[SLAB + i*NN + 4] = hB[i][4];
            }
        }
        if (sBot) {
            #pragma unroll
            for (int i = 0; i < 5; ++i) {
                *(f4*)(sBot + i*NN) = (f4){ hA[i][0], hA[i][1], hA[i][2], hA[i][3] };
                sBot[i*NN + 4] = hA[i][4];
                *(f4*)(sBot + SLAB + i*NN) = (f4){ hB[i][0], hB[i][1], hB[i][2], hB[i][3] };
                sBot[SLAB + i*NN + 4] = hB[i][4];
            }
        }
        __threadfence();
        __syncthreads();
        if (tid == 0) {
            __hip_atomic_fetch_add(flagSelf, 1, __ATOMIC_RELEASE, __HIP_MEMORY_SCOPE_AGENT);
            if (blk > 0)
                while (__hip_atomic_load(flagUp, __ATOMIC_ACQUIRE, __HIP_MEMORY_SCOPE_AGENT) < g + 1) {}
            if (blk < NBK-1)
                while (__hip_atomic_load(flagDn, __ATOMIC_ACQUIRE, __HIP_MEMORY_SCOPE_AGENT) < g + 1) {}
        }
        __syncthreads();
        {
            const float* rp = rTop ? rTop : rBot;
            if (rp) {
                #pragma unroll
                for (int i = 0; i < 5; ++i) {
                    const f4 v1 = *(const f4*)(rp + i*NN);
                    hA[i][0] = v1[0]; hA[i][1] = v1[1]; hA[i][2] = v1[2]; hA[i][3] = v1[3];
                    hA[i][4] = rp[i*NN + 4];
                    const f4 v2 = *(const f4*)(rp + SLAB + i*NN);
                    hB[i][0] = v2[0]; hB[i][1] = v2[1]; hB[i][2] = v2[2]; hB[i][3] = v2[3];
                    hB[i][4] = rp[SLAB + i*NN + 4];
                }
            }
        }
        // republish ALL edges into parity 0 (next round reads parity 0)
        PUBLISH(0);
        __syncthreads();
        g++;
    }
#undef ROUND
#undef PUBLISH
}

extern "C" void kernel_launch(void* const* d_in, const int* in_sizes, int n_in,
                              void* d_out, int out_size, void* d_ws, size_t ws_size,
                              hipStream_t stream) {
    const float* x    = (const float*)d_in[0];
    const float* cmat = (const float*)d_in[1];
    const float* rho  = (const float*)d_in[2];
    const int*   si   = (const int*)d_in[3];
    const int*   sj   = (const int*)d_in[4];
    const int*   pi   = (const int*)d_in[5];
    const int*   pj   = (const int*)d_in[6];
    float*       yout = (float*)d_out;
    float*       gbuf = (float*)d_ws;
    int*         flg  = (int*)((char*)d_ws + FLAG_OFF);

    // reset exchange flags every launch (graph-capture-safe)
    hipMemsetAsync(flg, 0, NB*NBK*sizeof(int), stream);

    wave_kernel<<<NB*8, NTHR, 0, stream>>>(x, cmat, rho, si, sj, pi, pj,
                                           yout, gbuf, flg);
}

// Round 15
// 712.073 us; speedup vs baseline: 1.2863x; 1.2863x over previous
//
#include <hip/hip_runtime.h>

// WaveRNN: 2D wave equation, T=512 steps, B=4 batches of 160x160.
// Ghost-zone decomposition: 4 blocks per batch (16 active blocks), OWN=40 rows
// owned + D=20 redundant halo rows/side; exchange h1+h2 boundary slabs through
// global memory every 20 steps (twice-validated protocol).
// R11 structure (passed) with intra-wave halo exchange via
// v_permlane32_swap_b32 + XOR identity: partner = rx ^ ry ^ own, which is
// exact and DIRECTION-INDEPENDENT (R14 failed by guessing the lane mapping).
// Inputs forced into distinct registers via inline-asm mov so the compiler
// cannot alias them (aliasing would break the identity).
// Per thread per step: 1x(b128+b32) LDS edge read + 1x(b128+b32) write only.

#define NB   4
#define NBK  4          // blocks per batch
#define OWN  40         // owned rows per block
#define D_EX 20         // halo depth == steps between exchanges
#define NT   512
#define NN   160
#define NP   32
#define C_DT 0.16f

#define TGX    32
#define TPR    16                // max patch-rows (interior: (40+2*20)/5)
#define NTHR   (TPR*TGX)         // 512
#define ESLOTS (TPR + 2)         // 18 edge slots; slot 0 and tail stay zero
#define K_ENT  6

#define SLAB      (D_EX*NN)              // floats per (side,level) slab: 3200
#define GB_FLOATS (NB*NBK*2*2*SLAB)      // 204800 floats = 819200 B
#define FLAG_OFF  (GB_FLOATS*4)          // byte offset of flags in d_ws

typedef float f4 __attribute__((ext_vector_type(4)));
typedef int   i2 __attribute__((ext_vector_type(2)));

#if defined(__has_builtin)
#if __has_builtin(__builtin_amdgcn_update_dpp)
#define HAVE_DPP 1
#endif
#endif

__device__ __forceinline__ float shr1(float v) {   // lane i <- lane i-1
#ifdef HAVE_DPP
    return __int_as_float(__builtin_amdgcn_update_dpp(
        0, __float_as_int(v), 0x138 /*wave_shr:1*/, 0xf, 0xf, true));
#else
    return __shfl_up(v, 1, 64);
#endif
}
__device__ __forceinline__ float shl1(float v) {   // lane i <- lane i+1
#ifdef HAVE_DPP
    return __int_as_float(__builtin_amdgcn_update_dpp(
        0, __float_as_int(v), 0x130 /*wave_shl:1*/, 0xf, 0xf, true));
#else
    return __shfl_down(v, 1, 64);
#endif
}

// VALU cross-half exchange, direction-independent:
// With DISTINCT input registers, permlane32_swap returns {a',b'} where at
// every lane exactly one of {a',b'} is the partner lane's value (lane^32) and
// the other is the own value. XOR identity recovers the partner exactly.
__device__ __forceinline__ float swap32(float v) {
    const int vi = __float_as_int(v);
    int vc;
    asm volatile("v_mov_b32 %0, %1" : "=v"(vc) : "v"(vi));  // force distinct reg
    const i2 r = __builtin_amdgcn_permlane32_swap(vc, vi, false, false);
    return __int_as_float(r.x ^ r.y ^ vi);
}

__global__ __launch_bounds__(NTHR, 1) void wave_kernel(
    const float* __restrict__ x,      // [B][T]
    const float* __restrict__ cmat,   // [N][N]
    const float* __restrict__ rho,    // [N][N]
    const int*   __restrict__ src_i_p,
    const int*   __restrict__ src_j_p,
    const int*   __restrict__ probe_i,// [P]
    const int*   __restrict__ probe_j,// [P]
    float*       __restrict__ y,      // [B][T][P]
    float*       __restrict__ gw,     // exchange slabs [B][NBK][side][lvl][20][160]
    int*         __restrict__ flags)  // [B*NBK], zeroed per launch
{
    // One published edge row per patch-row, double-buffered by parity.
    // Even patch-row pr publishes its row 0 at slot pr+1 (read by pr-1 as south);
    // odd pr publishes its row 4 at slot pr+1 (read by pr+1 as north).
    // Even pr reads slot pr (north); odd pr reads slot pr+2 (south).
    __shared__ f4    eb4[2][ESLOTS][TGX];
    __shared__ float eb1[2][ESLOTS][TGX];
    __shared__ float xbuf[NT];
    __shared__ int   pco[2*NP];

    const int bid   = blockIdx.x;
    const int batch = bid & 7;        // same-batch blocks likely share an XCD
    if (batch >= NB) return;          // idle pad blocks exit immediately
    const int blk   = bid >> 3;

    const int own_s = blk * OWN;
    const int own_e = own_s + OWN;
    const int ext_s = (own_s - D_EX < 0)  ? 0  : own_s - D_EX;
    const int ext_e = (own_e + D_EX > NN) ? NN : own_e + D_EX;
    const int npr   = (ext_e - ext_s) / 5;   // always even (8, 12, or 16)

    const int tid = threadIdx.x;
    const int pr  = tid >> 5;
    const int cg  = tid & 31;
    const int oddr = pr & 1;          // lanes 32-63 of each wave
    const bool act = pr < npr;
    const int gr0 = ext_s + 5*pr;     // global row of patch top (valid if act)
    const int c0  = 5*cg;

    // ---- init LDS (zero both parities: initial field is 0) ----
    {
        float* e4 = (float*)&eb4[0][0][0];
        for (int i = tid; i < 2*ESLOTS*TGX*4; i += NTHR) e4[i] = 0.0f;
        float* e1 = &eb1[0][0][0];
        for (int i = tid; i < 2*ESLOTS*TGX; i += NTHR) e1[i] = 0.0f;
        for (int i = tid; i < NT; i += NTHR) xbuf[i] = x[batch*NT + i];
        if (tid < NP) { pco[tid] = probe_i[tid]; pco[NP + tid] = probe_j[tid]; }
    }

    const int si = src_i_p[0];
    const int sj = src_j_p[0];

    float hA[5][5], hB[5][5], cf[5][5], c2[5][5];
    #pragma unroll
    for (int i = 0; i < 5; ++i)
        #pragma unroll
        for (int j = 0; j < 5; ++j) {
            float cfv = 0.0f;
            if (act) {
                const float cc = cmat[(gr0+i)*NN + (c0+j)];
                const float rr = rho[(gr0+i)*NN + (c0+j)];
                cfv = C_DT * cc * cc / rr;
            }
            cf[i][j] = cfv;
            c2[i][j] = 2.0f - 4.0f * cfv;
            hA[i][j] = 0.0f;
            hB[i][j] = 0.0f;
        }

    unsigned srcMask = 0;
    if (act && gr0 <= si && si < gr0 + 5 && c0 <= sj && sj < c0 + 5)
        srcMask = 1u << ((si - gr0)*5 + (sj - c0));

    __syncthreads();

    // per-thread probe entries over OWNED cells only (exact every step)
    unsigned long long ent = 0;
    int ecnt = 0;
    if (act && gr0 >= own_s && gr0 < own_e) {
        for (int p = 0; p < NP; ++p) {
            const int r = pco[p], c = pco[NP + p];
            if (r >= gr0 && r < gr0 + 5 && c >= c0 && c < c0 + 5) {
                const int ij = (r - gr0)*5 + (c - c0);
                if (ecnt < K_ENT)
                    ent |= ((unsigned long long)(unsigned)(p | (ij << 5))) << (10*ecnt);
                ecnt++;
            }
        }
    }

    // ---- exchange pointers (per-thread constant) ----
    const int bid2 = batch*NBK + blk;
    float* sTop = nullptr; float* sBot = nullptr;
    const float* rTop = nullptr; const float* rBot = nullptr;
    if (blk > 0 && gr0 >= own_s && gr0 < own_s + D_EX)
        sTop = gw + (size_t)(bid2*2 + 0)*2*SLAB + (gr0 - own_s)*NN + c0;
    if (blk < NBK-1 && gr0 >= own_e - D_EX && gr0 < own_e)
        sBot = gw + (size_t)(bid2*2 + 1)*2*SLAB + (gr0 - (own_e - D_EX))*NN + c0;
    if (blk > 0 && act && gr0 < own_s)
        rTop = gw + (size_t)((bid2-1)*2 + 1)*2*SLAB + (gr0 - (own_s - D_EX))*NN + c0;
    if (blk < NBK-1 && act && gr0 >= own_e)
        rBot = gw + (size_t)((bid2+1)*2 + 0)*2*SLAB + (gr0 - own_e)*NN + c0;
    int* const flagSelf = &flags[bid2];
    int* const flagUp   = &flags[bid2 - 1];
    int* const flagDn   = &flags[bid2 + 1];

    float* const yb = y + (size_t)batch*NT*NP;

    // loop-invariant LDS addresses (per parity)
    const int rdSlot = oddr ? (pr + 2) : pr;     // <= 17, in bounds
    const int wrSlot = pr + 1;
    f4*    const rd4a = &eb4[0][rdSlot][cg]; f4*    const rd4b = &eb4[1][rdSlot][cg];
    float* const rd1a = &eb1[0][rdSlot][cg]; float* const rd1b = &eb1[1][rdSlot][cg];
    f4*    const wr4a = &eb4[0][wrSlot][cg]; f4*    const wr4b = &eb4[1][wrSlot][cg];
    float* const wr1a = &eb1[0][wrSlot][cg]; float* const wr1b = &eb1[1][wrSlot][cg];

#define STEP(HS, HD, TT, PIN, POUT)                                           \
    {                                                                         \
        const int tt = (TT);                                                  \
        /* inter-wave halo via LDS: even pr -> north row, odd pr -> south */  \
        const f4    l4 = *(PIN ? rd4b : rd4a);                                \
        const float l1 = *(PIN ? rd1b : rd1a);                                \
        /* intra-wave halo via permlane32_swap XOR identity (VALU) */         \
        float rcv[5];                                                         \
        _Pragma("unroll")                                                     \
        for (int j = 0; j < 5; ++j) {                                         \
            const float snd = oddr ? HS[0][j] : HS[4][j];                     \
            rcv[j] = swap32(snd);                                             \
        }                                                                     \
        /* column halos via DPP */                                            \
        float wh[5], eh[5];                                                   \
        _Pragma("unroll")                                                     \
        for (int i = 0; i < 5; ++i) {                                         \
            const float tw = shr1(HS[i][4]);                                  \
            wh[i] = (cg == 0) ? 0.0f : tw;                                    \
            const float te = shl1(HS[i][0]);                                  \
            eh[i] = (cg == TGX-1) ? 0.0f : te;                                \
        }                                                                     \
        /* interior rows 1..3 first: register-only deps hide LDS latency */   \
        _Pragma("unroll")                                                     \
        for (int i = 1; i < 4; ++i) {                                         \
            _Pragma("unroll")                                                 \
            for (int j = 0; j < 5; ++j) {                                     \
                const float lf = (j == 0) ? wh[i] : HS[i][j-1];               \
                const float rt = (j == 4) ? eh[i] : HS[i][j+1];               \
                const float s  = (HS[i-1][j] + HS[i+1][j]) + (lf + rt);       \
                const float t1 = __builtin_fmaf(c2[i][j], HS[i][j], -HD[i][j]); \
                HD[i][j] = __builtin_fmaf(cf[i][j], s, t1);                   \
            }                                                                 \
        }                                                                     \
        /* boundary rows 0 and 4 (consume halos) */                           \
        _Pragma("unroll")                                                     \
        for (int j = 0; j < 5; ++j) {                                         \
            const float lv = (j==0)?l4[0]:(j==1)?l4[1]:(j==2)?l4[2]:(j==3)?l4[3]:l1; \
            const float nh = oddr ? rcv[j] : lv;                              \
            const float sh = oddr ? lv : rcv[j];                              \
            {                                                                 \
                const float lf = (j == 0) ? wh[0] : HS[0][j-1];               \
                const float rt = (j == 4) ? eh[0] : HS[0][j+1];               \
                const float s  = (nh + HS[1][j]) + (lf + rt);                 \
                const float t1 = __builtin_fmaf(c2[0][j], HS[0][j], -HD[0][j]); \
                HD[0][j] = __builtin_fmaf(cf[0][j], s, t1);                   \
            }                                                                 \
            {                                                                 \
                const float lf = (j == 0) ? wh[4] : HS[4][j-1];               \
                const float rt = (j == 4) ? eh[4] : HS[4][j+1];               \
                const float s  = (HS[3][j] + sh) + (lf + rt);                 \
                const float t1 = __builtin_fmaf(c2[4][j], HS[4][j], -HD[4][j]); \
                HD[4][j] = __builtin_fmaf(cf[4][j], s, t1);                   \
            }                                                                 \
        }                                                                     \
        if (srcMask) {                                                        \
            const float xt = xbuf[tt];                                        \
            _Pragma("unroll")                                                 \
            for (int i = 0; i < 5; ++i)                                       \
                _Pragma("unroll")                                             \
                for (int j = 0; j < 5; ++j)                                   \
                    if (srcMask & (1u << (i*5 + j))) HD[i][j] += xt;          \
        }                                                                     \
        /* publish my single edge row (even: new row 0, odd: new row 4) */    \
        {                                                                     \
            const f4 ev = (f4){ oddr ? HD[4][0] : HD[0][0],                   \
                                oddr ? HD[4][1] : HD[0][1],                   \
                                oddr ? HD[4][2] : HD[0][2],                   \
                                oddr ? HD[4][3] : HD[0][3] };                 \
            *(POUT ? wr4b : wr4a) = ev;                                       \
            *(POUT ? wr1b : wr1a) = oddr ? HD[4][4] : HD[0][4];               \
        }                                                                     \
        if (ecnt) {                                                           \
            float* const yt = yb + (size_t)tt * NP;                           \
            _Pragma("unroll")                                                 \
            for (int k2 = 0; k2 < K_ENT; ++k2) {                              \
                if (k2 < ecnt) {                                              \
                    const int e  = (int)((ent >> (10*k2)) & 0x3FF);           \
                    const int p  = e & 31;                                    \
                    const int ij = e >> 5;                                    \
                    float v = 0.0f;                                           \
                    _Pragma("unroll")                                         \
                    for (int i = 0; i < 5; ++i)                               \
                        _Pragma("unroll")                                     \
                        for (int j = 0; j < 5; ++j)                           \
                            if (ij == i*5 + j) v = HD[i][j];                  \
                    yt[p] = v;                                                \
                }                                                             \
            }                                                                 \
        }                                                                     \
        __syncthreads();                                                      \
    }

    int t = 0, g = 0;
    while (t < NT) {
        const int steps = (NT - t < D_EX) ? (NT - t) : D_EX;
        for (int k = 0; k < steps; k += 2) {
            STEP(hA, hB, t + k,     0, 1);
            STEP(hB, hA, t + k + 1, 1, 0);
        }
        t += steps;
        if (t >= NT) break;

        // ---- boundary exchange (h1=hA, h2=hB; t is even) ----
        if (sTop) {
            #pragma unroll
            for (int i = 0; i < 5; ++i) {
                *(f4*)(sTop + i*NN) = (f4){ hA[i][0], hA[i][1], hA[i][2], hA[i][3] };
                sTop[i*NN + 4] = hA[i][4];
                *(f4*)(sTop + SLAB + i*NN) = (f4){ hB[i][0], hB[i][1], hB[i][2], hB[i][3] };
                sTop[SLAB + i*NN + 4] = hB[i][4];
            }
        }
        if (sBot) {
            #pragma unroll
            for (int i = 0; i < 5; ++i) {
                *(f4*)(sBot + i*NN) = (f4){ hA[i][0], hA[i][1], hA[i][2], hA[i][3] };
                sBot[i*NN + 4] = hA[i][4];
                *(f4*)(sBot + SLAB + i*NN) = (f4){ hB[i][0], hB[i][1], hB[i][2], hB[i][3] };
                sBot[SLAB + i*NN + 4] = hB[i][4];
            }
        }
        __threadfence();
        __syncthreads();
        if (tid == 0) {
            __hip_atomic_fetch_add(flagSelf, 1, __ATOMIC_RELEASE, __HIP_MEMORY_SCOPE_AGENT);
            if (blk > 0)
                while (__hip_atomic_load(flagUp, __ATOMIC_ACQUIRE, __HIP_MEMORY_SCOPE_AGENT) < g + 1) {}
            if (blk < NBK-1)
                while (__hip_atomic_load(flagDn, __ATOMIC_ACQUIRE, __HIP_MEMORY_SCOPE_AGENT) < g + 1) {}
        }
        __syncthreads();
        {
            const float* rp = rTop ? rTop : rBot;
            if (rp) {
                #pragma unroll
                for (int i = 0; i < 5; ++i) {
                    const f4 v1 = *(const f4*)(rp + i*NN);
                    hA[i][0] = v1[0]; hA[i][1] = v1[1]; hA[i][2] = v1[2]; hA[i][3] = v1[3];
                    hA[i][4] = rp[i*NN + 4];
                    const f4 v2 = *(const f4*)(rp + SLAB + i*NN);
                    hB[i][0] = v2[0]; hB[i][1] = v2[1]; hB[i][2] = v2[2]; hB[i][3] = v2[3];
                    hB[i][4] = rp[SLAB + i*NN + 4];
                }
                // republish refreshed edge into parity 0 (next step reads PIN=0)
                const f4 rv = (f4){ oddr ? hA[4][0] : hA[0][0],
                                    oddr ? hA[4][1] : hA[0][1],
                                    oddr ? hA[4][2] : hA[0][2],
                                    oddr ? hA[4][3] : hA[0][3] };
                *wr4a = rv;
                *wr1a = oddr ? hA[4][4] : hA[0][4];
            }
        }
        __syncthreads();
        g++;
    }
#undef STEP
}

extern "C" void kernel_launch(void* const* d_in, const int* in_sizes, int n_in,
                              void* d_out, int out_size, void* d_ws, size_t ws_size,
                              hipStream_t stream) {
    const float* x    = (const float*)d_in[0];
    const float* cmat = (const float*)d_in[1];
    const float* rho  = (const float*)d_in[2];
    const int*   si   = (const int*)d_in[3];
    const int*   sj   = (const int*)d_in[4];
    const int*   pi   = (const int*)d_in[5];
    const int*   pj   = (const int*)d_in[6];
    float*       yout = (float*)d_out;
    float*       gbuf = (float*)d_ws;
    int*         flg  = (int*)((char*)d_ws + FLAG_OFF);

    // reset exchange flags every launch (graph-capture-safe)
    hipMemsetAsync(flg, 0, NB*NBK*sizeof(int), stream);

    wave_kernel<<<NB*8, NTHR, 0, stream>>>(x, cmat, rho, si, sj, pi, pj,
                                           yout, gbuf, flg);
}

// Round 16
// 643.223 us; speedup vs baseline: 1.4239x; 1.1070x over previous
//
#include <hip/hip_runtime.h>

// WaveRNN: 2D wave equation, T=512 steps, B=4 batches of 160x160.
// FINAL: restore of round-9 kernel (best measured: 646us, passed twice-
// validated). Ghost-zone decomposition: 4 blocks per batch (16 active),
// OWN=40 rows owned + D=20 redundant halo rows/side; exchange h1+h2 boundary
// slabs through global memory every 20 steps (threadfence + release-RMW +
// acquire-per-poll spin). Intra-block: 5x5 register patches, DPP column
// halos, split f4+f1 LDS edge rows, double-buffered parity -> 1 barrier/step;
// per-step probe stores by owning thread.
// Structural floor (measured across R10-R15 variants): ~1.08us/step from the
// barrier-coupled LDS round-trip of the sequential recurrence; insensitive to
// LDS-traffic reduction, CU count, wave count, and temporal blocking.

#define NB   4
#define NBK  4          // blocks per batch
#define OWN  40         // owned rows per block
#define D_EX 20         // halo depth == steps between exchanges
#define NT   512
#define NN   160
#define NP   32
#define C_DT 0.16f

#define TGX   32
#define TPR   16                 // max patch-rows (interior: (40+2*20)/5)
#define NTHR  (TPR*TGX)          // 512
#define EROWS (2*TPR + 2)        // 34; slots 0 and 33 are zero guards
#define K_ENT 6

#define SLAB      (D_EX*NN)              // floats per (side,level) slab: 3200
#define GB_FLOATS (NB*NBK*2*2*SLAB)      // 204800 floats = 819200 B
#define FLAG_OFF  (GB_FLOATS*4)          // byte offset of flags in d_ws

typedef float f4 __attribute__((ext_vector_type(4)));

#if defined(__has_builtin)
#if __has_builtin(__builtin_amdgcn_update_dpp)
#define HAVE_DPP 1
#endif
#endif

__device__ __forceinline__ float shr1(float v) {   // lane i <- lane i-1
#ifdef HAVE_DPP
    return __int_as_float(__builtin_amdgcn_update_dpp(
        0, __float_as_int(v), 0x138 /*wave_shr:1*/, 0xf, 0xf, true));
#else
    return __shfl_up(v, 1, 64);
#endif
}
__device__ __forceinline__ float shl1(float v) {   // lane i <- lane i+1
#ifdef HAVE_DPP
    return __int_as_float(__builtin_amdgcn_update_dpp(
        0, __float_as_int(v), 0x130 /*wave_shl:1*/, 0xf, 0xf, true));
#else
    return __shfl_down(v, 1, 64);
#endif
}

__global__ __launch_bounds__(NTHR, 1) void wave_kernel(
    const float* __restrict__ x,      // [B][T]
    const float* __restrict__ cmat,   // [N][N]
    const float* __restrict__ rho,    // [N][N]
    const int*   __restrict__ src_i_p,
    const int*   __restrict__ src_j_p,
    const int*   __restrict__ probe_i,// [P]
    const int*   __restrict__ probe_j,// [P]
    float*       __restrict__ y,      // [B][T][P]
    float*       __restrict__ gw,     // exchange slabs [B][NBK][side][lvl][20][160]
    int*         __restrict__ flags)  // [B*NBK], zeroed per launch
{
    __shared__ f4    eb4[2][EROWS][TGX];
    __shared__ float eb1[2][EROWS][TGX];
    __shared__ float xbuf[NT];
    __shared__ int   pco[2*NP];

    const int bid   = blockIdx.x;
    const int batch = bid & 7;        // same-batch blocks likely share an XCD
    if (batch >= NB) return;          // idle pad blocks exit immediately
    const int blk   = bid >> 3;

    const int own_s = blk * OWN;
    const int own_e = own_s + OWN;
    const int ext_s = (own_s - D_EX < 0)  ? 0  : own_s - D_EX;
    const int ext_e = (own_e + D_EX > NN) ? NN : own_e + D_EX;
    const int npr   = (ext_e - ext_s) / 5;

    const int tid = threadIdx.x;
    const int pr  = tid >> 5;
    const int cg  = tid & 31;
    const bool act = pr < npr;
    const int gr0 = ext_s + 5*pr;     // global row of patch top (valid if act)
    const int c0  = 5*cg;

    // ---- init LDS ----
    {
        float* e4 = (float*)&eb4[0][0][0];
        for (int i = tid; i < 2*EROWS*TGX*4; i += NTHR) e4[i] = 0.0f;
        float* e1 = &eb1[0][0][0];
        for (int i = tid; i < 2*EROWS*TGX; i += NTHR) e1[i] = 0.0f;
        for (int i = tid; i < NT; i += NTHR) xbuf[i] = x[batch*NT + i];
        if (tid < NP) { pco[tid] = probe_i[tid]; pco[NP + tid] = probe_j[tid]; }
    }

    const int si = src_i_p[0];
    const int sj = src_j_p[0];

    float hA[5][5], hB[5][5], cf[5][5], c2[5][5];
    #pragma unroll
    for (int i = 0; i < 5; ++i)
        #pragma unroll
        for (int j = 0; j < 5; ++j) {
            float cfv = 0.0f;
            if (act) {
                const float cc = cmat[(gr0+i)*NN + (c0+j)];
                const float rr = rho[(gr0+i)*NN + (c0+j)];
                cfv = C_DT * cc * cc / rr;
            }
            cf[i][j] = cfv;
            c2[i][j] = 2.0f - 4.0f * cfv;
            hA[i][j] = 0.0f;
            hB[i][j] = 0.0f;
        }

    unsigned srcMask = 0;
    if (act && gr0 <= si && si < gr0 + 5 && c0 <= sj && sj < c0 + 5)
        srcMask = 1u << ((si - gr0)*5 + (sj - c0));

    __syncthreads();

    // per-thread probe entries over OWNED cells only (exact every step)
    unsigned long long ent = 0;
    int ecnt = 0;
    if (act && gr0 >= own_s && gr0 < own_e) {
        for (int p = 0; p < NP; ++p) {
            const int r = pco[p], c = pco[NP + p];
            if (r >= gr0 && r < gr0 + 5 && c >= c0 && c < c0 + 5) {
                const int ij = (r - gr0)*5 + (c - c0);
                if (ecnt < K_ENT)
                    ent |= ((unsigned long long)(unsigned)(p | (ij << 5))) << (10*ecnt);
                ecnt++;
            }
        }
    }

    // ---- exchange pointers (per-thread constant) ----
    const int bid2 = batch*NBK + blk;
    float* sTop = nullptr; float* sBot = nullptr;
    const float* rTop = nullptr; const float* rBot = nullptr;
    if (blk > 0 && gr0 >= own_s && gr0 < own_s + D_EX)
        sTop = gw + (size_t)(bid2*2 + 0)*2*SLAB + (gr0 - own_s)*NN + c0;
    if (blk < NBK-1 && gr0 >= own_e - D_EX && gr0 < own_e)
        sBot = gw + (size_t)(bid2*2 + 1)*2*SLAB + (gr0 - (own_e - D_EX))*NN + c0;
    if (blk > 0 && act && gr0 < own_s)
        rTop = gw + (size_t)((bid2-1)*2 + 1)*2*SLAB + (gr0 - (own_s - D_EX))*NN + c0;
    if (blk < NBK-1 && act && gr0 >= own_e)
        rBot = gw + (size_t)((bid2+1)*2 + 0)*2*SLAB + (gr0 - own_e)*NN + c0;
    int* const flagSelf = &flags[bid2];
    int* const flagUp   = &flags[bid2 - 1];
    int* const flagDn   = &flags[bid2 + 1];

    float* const yb = y + (size_t)batch*NT*NP;

#define STEP(HS, HD, TT, PIN, POUT)                                           \
    {                                                                         \
        const int tt = (TT);                                                  \
        const f4    nh4 = eb4[PIN][2*pr    ][cg];                             \
        const float nhe = eb1[PIN][2*pr    ][cg];                             \
        const f4    sh4 = eb4[PIN][2*pr + 3][cg];                             \
        const float she = eb1[PIN][2*pr + 3][cg];                             \
        const float nh[5] = { nh4[0], nh4[1], nh4[2], nh4[3], nhe };          \
        const float sh[5] = { sh4[0], sh4[1], sh4[2], sh4[3], she };          \
        float wh[5], eh[5];                                                   \
        _Pragma("unroll")                                                     \
        for (int i = 0; i < 5; ++i) {                                         \
            const float tw = shr1(HS[i][4]);                                  \
            wh[i] = (cg == 0) ? 0.0f : tw;                                    \
            const float te = shl1(HS[i][0]);                                  \
            eh[i] = (cg == TGX-1) ? 0.0f : te;                                \
        }                                                                     \
        _Pragma("unroll")                                                     \
        for (int i = 0; i < 5; ++i) {                                         \
            _Pragma("unroll")                                                 \
            for (int j = 0; j < 5; ++j) {                                     \
                const float up = (i == 0) ? nh[j] : HS[i-1][j];               \
                const float dn = (i == 4) ? sh[j] : HS[i+1][j];               \
                const float lf = (j == 0) ? wh[i] : HS[i][j-1];               \
                const float rt = (j == 4) ? eh[i] : HS[i][j+1];               \
                const float s  = (up + dn) + (lf + rt);                       \
                const float t1 = __builtin_fmaf(c2[i][j], HS[i][j], -HD[i][j]); \
                HD[i][j] = __builtin_fmaf(cf[i][j], s, t1);                   \
            }                                                                 \
        }                                                                     \
        if (srcMask) {                                                        \
            const float xt = xbuf[tt];                                        \
            _Pragma("unroll")                                                 \
            for (int i = 0; i < 5; ++i)                                       \
                _Pragma("unroll")                                             \
                for (int j = 0; j < 5; ++j)                                   \
                    if (srcMask & (1u << (i*5 + j))) HD[i][j] += xt;          \
        }                                                                     \
        eb4[POUT][2*pr + 1][cg] = (f4){ HD[0][0], HD[0][1], HD[0][2], HD[0][3] }; \
        eb1[POUT][2*pr + 1][cg] = HD[0][4];                                   \
        eb4[POUT][2*pr + 2][cg] = (f4){ HD[4][0], HD[4][1], HD[4][2], HD[4][3] }; \
        eb1[POUT][2*pr + 2][cg] = HD[4][4];                                   \
        if (ecnt) {                                                           \
            float* const yt = yb + (size_t)tt * NP;                           \
            _Pragma("unroll")                                                 \
            for (int k = 0; k < K_ENT; ++k) {                                 \
                if (k < ecnt) {                                               \
                    const int e  = (int)((ent >> (10*k)) & 0x3FF);            \
                    const int p  = e & 31;                                    \
                    const int ij = e >> 5;                                    \
                    float v = 0.0f;                                           \
                    _Pragma("unroll")                                         \
                    for (int i = 0; i < 5; ++i)                               \
                        _Pragma("unroll")                                     \
                        for (int j = 0; j < 5; ++j)                           \
                            if (ij == i*5 + j) v = HD[i][j];                  \
                    yt[p] = v;                                                \
                }                                                             \
            }                                                                 \
        }                                                                     \
        __syncthreads();                                                      \
    }

    int t = 0, g = 0;
    while (t < NT) {
        const int steps = (NT - t < D_EX) ? (NT - t) : D_EX;
        for (int k = 0; k < steps; k += 2) {
            STEP(hA, hB, t + k,     0, 1);
            STEP(hB, hA, t + k + 1, 1, 0);
        }
        t += steps;
        if (t >= NT) break;

        // ---- boundary exchange (h1=hA, h2=hB; t is even) ----
        if (sTop) {
            #pragma unroll
            for (int i = 0; i < 5; ++i) {
                *(f4*)(sTop + i*NN) = (f4){ hA[i][0], hA[i][1], hA[i][2], hA[i][3] };
                sTop[i*NN + 4] = hA[i][4];
                *(f4*)(sTop + SLAB + i*NN) = (f4){ hB[i][0], hB[i][1], hB[i][2], hB[i][3] };
                sTop[SLAB + i*NN + 4] = hB[i][4];
            }
        }
        if (sBot) {
            #pragma unroll
            for (int i = 0; i < 5; ++i) {
                *(f4*)(sBot + i*NN) = (f4){ hA[i][0], hA[i][1], hA[i][2], hA[i][3] };
                sBot[i*NN + 4] = hA[i][4];
                *(f4*)(sBot + SLAB + i*NN) = (f4){ hB[i][0], hB[i][1], hB[i][2], hB[i][3] };
                sBot[SLAB + i*NN + 4] = hB[i][4];
            }
        }
        __threadfence();
        __syncthreads();
        if (tid == 0) {
            __hip_atomic_fetch_add(flagSelf, 1, __ATOMIC_RELEASE, __HIP_MEMORY_SCOPE_AGENT);
            if (blk > 0)
                while (__hip_atomic_load(flagUp, __ATOMIC_ACQUIRE, __HIP_MEMORY_SCOPE_AGENT) < g + 1) {}
            if (blk < NBK-1)
                while (__hip_atomic_load(flagDn, __ATOMIC_ACQUIRE, __HIP_MEMORY_SCOPE_AGENT) < g + 1) {}
        }
        __syncthreads();
        {
            const float* rp = rTop ? rTop : rBot;
            if (rp) {
                #pragma unroll
                for (int i = 0; i < 5; ++i) {
                    const f4 v1 = *(const f4*)(rp + i*NN);
                    hA[i][0] = v1[0]; hA[i][1] = v1[1]; hA[i][2] = v1[2]; hA[i][3] = v1[3];
                    hA[i][4] = rp[i*NN + 4];
                    const f4 v2 = *(const f4*)(rp + SLAB + i*NN);
                    hB[i][0] = v2[0]; hB[i][1] = v2[1]; hB[i][2] = v2[2]; hB[i][3] = v2[3];
                    hB[i][4] = rp[SLAB + i*NN + 4];
                }
                // republish refreshed edges into parity 0 (next step reads PIN=0)
                eb4[0][2*pr + 1][cg] = (f4){ hA[0][0], hA[0][1], hA[0][2], hA[0][3] };
                eb1[0][2*pr + 1][cg] = hA[0][4];
                eb4[0][2*pr + 2][cg] = (f4){ hA[4][0], hA[4][1], hA[4][2], hA[4][3] };
                eb1[0][2*pr + 2][cg] = hA[4][4];
            }
        }
        __syncthreads();
        g++;
    }
#undef STEP
}

extern "C" void kernel_launch(void* const* d_in, const int* in_sizes, int n_in,
                              void* d_out, int out_size, void* d_ws, size_t ws_size,
                              hipStream_t stream) {
    const float* x    = (const float*)d_in[0];
    const float* cmat = (const float*)d_in[1];
    const float* rho  = (const float*)d_in[2];
    const int*   si   = (const int*)d_in[3];
    const int*   sj   = (const int*)d_in[4];
    const int*   pi   = (const int*)d_in[5];
    const int*   pj   = (const int*)d_in[6];
    float*       yout = (float*)d_out;
    float*       gbuf = (float*)d_ws;
    int*         flg  = (int*)((char*)d_ws + FLAG_OFF);

    // reset exchange flags every launch (graph-capture-safe)
    hipMemsetAsync(flg, 0, NB*NBK*sizeof(int), stream);

    wave_kernel<<<NB*8, NTHR, 0, stream>>>(x, cmat, rho, si, sj, pi, pj,
                                           yout, gbuf, flg);
}